// Round 1
// baseline (1643.647 us; speedup 1.0000x reference)
//
#include <hip/hip_runtime.h>
#include <math.h>

#define BB 8
#define CC 32
#define RR 2048
#define II 64
#define OO 64

// ---------------------------------------------------------------------------
// K1: priors[b,c,r,o] = sum_i x[b,c,r,i] * W[c,r,i,o]
// grid = C * (R/16) = 4096 blocks, 256 threads.
// thread: og = tid%16 -> o0 = og*4 (4 consecutive o's), rl = tid/16 (16 r's/block)
// x tile staged in LDS with row stride 68 floats (272 B): the 4 distinct
// r_local addresses per wave land on disjoint bank quads -> conflict-free b128.
// ---------------------------------------------------------------------------
__global__ __launch_bounds__(256) void priors_kernel(const float* __restrict__ x,
                                                     const float* __restrict__ w,
                                                     float* __restrict__ priors) {
    __shared__ float xs[8 * 16 * 68];  // [b*16+rl][68], 34816 B
    const int tid = threadIdx.x;
    const int blk = blockIdx.x;
    const int c  = blk >> 7;           // 128 blocks per c
    const int r0 = (blk & 127) << 4;   // 16 r per block

    // cooperative x load: 128 rows x 64 floats = 2048 float4
    for (int l = tid; l < 2048; l += 256) {
        const int row = l >> 4;            // b*16 + rl
        const int i4  = (l & 15) << 2;
        const int b   = row >> 4;
        const int rl  = row & 15;
        const float4 xv = *(const float4*)(x + ((size_t)(b * CC + c) * RR + (size_t)(r0 + rl)) * II + i4);
        *(float4*)(xs + row * 68 + i4) = xv;
    }
    __syncthreads();

    const int og = tid & 15;
    const int rl = tid >> 4;
    const int o0 = og << 2;
    const int r  = r0 + rl;
    const float* wbase = w + ((size_t)c * RR + r) * II * OO + o0;

    float4 acc[8];
#pragma unroll
    for (int b = 0; b < 8; ++b) acc[b] = make_float4(0.f, 0.f, 0.f, 0.f);

#pragma unroll 4
    for (int ii = 0; ii < 16; ++ii) {
        const int i0 = ii << 2;
        const float4 w0 = *(const float4*)(wbase + (size_t)(i0 + 0) * OO);
        const float4 w1 = *(const float4*)(wbase + (size_t)(i0 + 1) * OO);
        const float4 w2 = *(const float4*)(wbase + (size_t)(i0 + 2) * OO);
        const float4 w3 = *(const float4*)(wbase + (size_t)(i0 + 3) * OO);
#pragma unroll
        for (int b = 0; b < 8; ++b) {
            const float4 xv = *(const float4*)(xs + (b * 16 + rl) * 68 + i0);
            acc[b].x += xv.x * w0.x + xv.y * w1.x + xv.z * w2.x + xv.w * w3.x;
            acc[b].y += xv.x * w0.y + xv.y * w1.y + xv.z * w2.y + xv.w * w3.y;
            acc[b].z += xv.x * w0.z + xv.y * w1.z + xv.z * w2.z + xv.w * w3.z;
            acc[b].w += xv.x * w0.w + xv.y * w1.w + xv.z * w2.w + xv.w * w3.w;
        }
    }

#pragma unroll
    for (int b = 0; b < 8; ++b) {
        *(float4*)(priors + ((size_t)(b * CC + c) * RR + r) * OO + o0) = acc[b];
    }
}

// ---------------------------------------------------------------------------
// K2: s[bc,o] = (1/R) * sum_r priors[bc,r,o]   (iteration 0: uniform softmax)
// grid = B*C = 256 blocks, 512 threads. quad = tid%16 (o0=quad*4), rg = tid/16.
// ---------------------------------------------------------------------------
__global__ __launch_bounds__(512) void s0_kernel(const float* __restrict__ priors,
                                                 float* __restrict__ s) {
    const int tid  = threadIdx.x;
    const int bc   = blockIdx.x;
    const int quad = tid & 15;
    const int rg   = tid >> 4;     // 0..31
    const int o0   = quad << 2;
    const float* base = priors + (size_t)bc * RR * OO;

    float4 acc = make_float4(0.f, 0.f, 0.f, 0.f);
    for (int r = rg; r < RR; r += 32) {
        const float4 p = *(const float4*)(base + (size_t)r * OO + o0);
        acc.x += p.x; acc.y += p.y; acc.z += p.z; acc.w += p.w;
    }

    __shared__ float4 red[512];
    red[tid] = acc;
    __syncthreads();
    for (int off = 16; off > 0; off >>= 1) {
        if (rg < off) {
            float4 a = red[tid];
            const float4 b2 = red[tid + off * 16];
            a.x += b2.x; a.y += b2.y; a.z += b2.z; a.w += b2.w;
            red[tid] = a;
        }
        __syncthreads();
    }
    if (rg == 0) {
        float4 a = red[quad];
        const float inv = 1.0f / (float)RR;
        a.x *= inv; a.y *= inv; a.z *= inv; a.w *= inv;
        *(float4*)(s + (size_t)bc * OO + o0) = a;
    }
}

// ---------------------------------------------------------------------------
// squash: n2 = sum(s^2) over all 16384 elems (global Frobenius norm, per ref);
// v = s * sqrt(n2)/(1+n2). accumulate=1 -> dst += v (running vsum for logits).
// single block, 256 threads.
// ---------------------------------------------------------------------------
__global__ __launch_bounds__(256) void squash_kernel(const float* __restrict__ s,
                                                     float* __restrict__ dst,
                                                     int accumulate) {
    const int tid = threadIdx.x;
    const int N = BB * CC * OO;
    float part = 0.f;
    for (int idx = tid; idx < N; idx += 256) {
        const float val = s[idx];
        part += val * val;
    }
    for (int off = 32; off > 0; off >>= 1) part += __shfl_down(part, off, 64);
    __shared__ float wsum[4];
    if ((tid & 63) == 0) wsum[tid >> 6] = part;
    __syncthreads();
    const float n2 = wsum[0] + wsum[1] + wsum[2] + wsum[3];
    const float scale = sqrtf(n2) / (1.0f + n2);
    for (int idx = tid; idx < N; idx += 256) {
        float val = s[idx] * scale;
        if (accumulate) val += dst[idx];
        dst[idx] = val;
    }
}

// ---------------------------------------------------------------------------
// route: per (b,c): t_r,o = priors[bc,r,o] * v[bc,o];
// s[bc,o] = sum_r softmax_r(t)_r,o * priors[bc,r,o]  via one-pass online softmax.
// grid = 256 blocks, 512 threads. Exact (m,l,ss) state merge across 32 r-groups.
// ---------------------------------------------------------------------------
__device__ __forceinline__ void online_update(float p, float vv, float& m, float& l, float& ss) {
    const float t  = p * vv;
    const float mn = fmaxf(m, t);
    const float c0 = __expf(m - mn);
    const float e  = __expf(t - mn);
    l  = l * c0 + e;
    ss = ss * c0 + e * p;
    m  = mn;
}

__device__ __forceinline__ void online_merge(float m1, float l1, float s1,
                                             float& M, float& L, float& S) {
    const float mn = fmaxf(M, m1);
    const float c0 = __expf(M - mn);
    const float c1 = __expf(m1 - mn);
    L = L * c0 + l1 * c1;
    S = S * c0 + s1 * c1;
    M = mn;
}

__global__ __launch_bounds__(512) void route_kernel(const float* __restrict__ priors,
                                                    const float* __restrict__ v,
                                                    float* __restrict__ s) {
    const int tid  = threadIdx.x;
    const int bc   = blockIdx.x;
    const int quad = tid & 15;
    const int rg   = tid >> 4;     // 0..31
    const int o0   = quad << 2;
    const float* base = priors + (size_t)bc * RR * OO;
    const float4 vv = *(const float4*)(v + (size_t)bc * OO + o0);

    float4 m  = make_float4(-INFINITY, -INFINITY, -INFINITY, -INFINITY);
    float4 l  = make_float4(0.f, 0.f, 0.f, 0.f);
    float4 ss = make_float4(0.f, 0.f, 0.f, 0.f);

    for (int r = rg; r < RR; r += 32) {
        const float4 p = *(const float4*)(base + (size_t)r * OO + o0);
        online_update(p.x, vv.x, m.x, l.x, ss.x);
        online_update(p.y, vv.y, m.y, l.y, ss.y);
        online_update(p.z, vv.z, m.z, l.z, ss.z);
        online_update(p.w, vv.w, m.w, l.w, ss.w);
    }

    __shared__ float4 ms[512], ls[512], sss[512];
    ms[tid] = m; ls[tid] = l; sss[tid] = ss;
    __syncthreads();

    if (tid < 16) {  // one thread per o-quad merges 32 partial states
        float4 M  = make_float4(-INFINITY, -INFINITY, -INFINITY, -INFINITY);
        float4 L  = make_float4(0.f, 0.f, 0.f, 0.f);
        float4 S  = make_float4(0.f, 0.f, 0.f, 0.f);
        for (int g = 0; g < 32; ++g) {
            const float4 m1 = ms[g * 16 + tid];
            const float4 l1 = ls[g * 16 + tid];
            const float4 s1 = sss[g * 16 + tid];
            online_merge(m1.x, l1.x, s1.x, M.x, L.x, S.x);
            online_merge(m1.y, l1.y, s1.y, M.y, L.y, S.y);
            online_merge(m1.z, l1.z, s1.z, M.z, L.z, S.z);
            online_merge(m1.w, l1.w, s1.w, M.w, L.w, S.w);
        }
        float4 out;
        out.x = S.x / L.x; out.y = S.y / L.y; out.z = S.z / L.z; out.w = S.w / L.w;
        *(float4*)(s + (size_t)bc * OO + tid * 4) = out;
    }
}

// ---------------------------------------------------------------------------
// Launch: priors -> s0 -> squash(v0) -> route(v0) -> squash(+v1) -> route ->
// squash -> d_out.  logits collapse to priors * vsum (vsum = v0 [+ v1]).
// ---------------------------------------------------------------------------
extern "C" void kernel_launch(void* const* d_in, const int* in_sizes, int n_in,
                              void* d_out, int out_size, void* d_ws, size_t ws_size,
                              hipStream_t stream) {
    const float* x = (const float*)d_in[0];
    const float* w = (const float*)d_in[1];
    // d_in[2] = iterations (=3, baked into the launch sequence)

    float* priors = (float*)d_ws;                       // B*C*R*O = 33.5M floats
    float* s      = priors + (size_t)BB * CC * RR * OO; // 16384 floats
    float* vsum   = s + (size_t)BB * CC * OO;           // 16384 floats
    float* out    = (float*)d_out;

    priors_kernel<<<CC * (RR / 16), 256, 0, stream>>>(x, w, priors);
    s0_kernel<<<BB * CC, 512, 0, stream>>>(priors, s);          // iter 0 (uniform)
    squash_kernel<<<1, 256, 0, stream>>>(s, vsum, 0);           // vsum = v0
    route_kernel<<<BB * CC, 512, 0, stream>>>(priors, vsum, s); // iter 1
    squash_kernel<<<1, 256, 0, stream>>>(s, vsum, 1);           // vsum += v1
    route_kernel<<<BB * CC, 512, 0, stream>>>(priors, vsum, s); // iter 2
    squash_kernel<<<1, 256, 0, stream>>>(s, out, 0);            // v2 -> output
}